// Round 3
// baseline (205.939 us; speedup 1.0000x reference)
//
#include <hip/hip_runtime.h>
#include <hip/hip_fp16.h>
#include <math.h>

#define NPROJ 96
#define NANG  96
#define DET   192
#define NPIX  16384            // 128*128
#define SLICE (NANG*DET)       // 18432

// DSD/DU = DSD/DV = 1000/3.5
#define KPROJ 285.7142857142857f

__device__ __forceinline__ float frcp(float x) { return __builtin_amdgcn_rcpf(x); }

__device__ __forceinline__ float ffract(float x) {
#if __has_builtin(__builtin_amdgcn_fractf)
    return __builtin_amdgcn_fractf(x);
#else
    return x - floorf(x);
#endif
}

typedef __fp16 h2 __attribute__((ext_vector_type(2)));

__device__ __forceinline__ unsigned pack2(float a, float b) {
    h2 p = __builtin_amdgcn_cvt_pkrtz(a, b);
    return __builtin_bit_cast(unsigned, p);
}
__device__ __forceinline__ h2 as_h2(unsigned u) { return __builtin_bit_cast(h2, u); }

#if __has_builtin(__builtin_amdgcn_fdot2)
#define FDOT2(a, b, c) __builtin_amdgcn_fdot2((a), (b), (c), false)
#else
__device__ __forceinline__ float FDOT2(h2 a, h2 b, float c) {
    return c + (float)a[0] * (float)b[0] + (float)a[1] * (float)b[1];
}
#endif

// ---------------------------------------------------------------------------
// Raw buffer loads (SRSRC): 32-bit voffset + SGPR soffset replaces 64-bit
// per-lane address adds on gathers (CK's llvm.amdgcn.raw.buffer.load idiom).
// ---------------------------------------------------------------------------
typedef int v4i   __attribute__((ext_vector_type(4)));
typedef unsigned u32x2 __attribute__((ext_vector_type(2)));

extern "C" __device__ u32x2    llvm_buf_load_x2(v4i rsrc, int voffset, int soffset, int aux) __asm("llvm.amdgcn.raw.buffer.load.v2i32");
extern "C" __device__ unsigned llvm_buf_load_x1(v4i rsrc, int voffset, int soffset, int aux) __asm("llvm.amdgcn.raw.buffer.load.i32");

__device__ __forceinline__ v4i make_srsrc(const void* p, unsigned bytes) {
    const unsigned long long a = (unsigned long long)p;
    v4i r;
    r.x = (int)(unsigned)(a & 0xffffffffull);
    r.y = (int)(unsigned)(a >> 32);       // base[47:32]; stride=0
    r.z = (int)bytes;                     // num_records in bytes (stride==0)
    r.w = 0x00020000;                     // raw untyped dword access
    return r;
}

// ---------------------------------------------------------------------------
// K1: deriv = grad_lastdim(sino * weight) -> DIFFERENCE pairs:
// derivp[row][d] = half2(g[d], g[d+1]-g[d])  =>  lerp weight is (1, f).
// ---------------------------------------------------------------------------
__global__ __launch_bounds__(192) void k_deriv(const float* __restrict__ sino,
                                               const float* __restrict__ wgt,
                                               unsigned* __restrict__ derivp) {
    __shared__ float row[DET];
    const int r = blockIdx.x;          // p*96 + a
    const int d = threadIdx.x;         // 0..191
    const int base = r * DET + d;
    row[d] = sino[base] * wgt[base];
    __syncthreads();
    auto grad = [&](int i) -> float {
        i = (i > DET-1) ? DET-1 : i;
        if (i == 0)       return row[1] - row[0];
        if (i == DET-1)   return row[DET-1] - row[DET-2];
        return 0.5f * (row[i+1] - row[i-1]);
    };
    const float g0 = grad(d), g1 = grad(d+1);
    derivp[base] = pack2(g0, g1 - g0);
}

// ---------------------------------------------------------------------------
// K2: 2D backprojection + cosine weighting — r13 winner main loop, now with
// SRSRC buffer gathers: voffset = i0<<2 (1 VALU), slice/angle offset in
// scalar soffset (p*73728 + a*768). Saves the 64-bit add pair per gather.
// Epilogue: every-v ROW-PAIR layout (uint2 per (v,u)):
//   wp[p][v][u] = { pr(v,u), pr(v+1,u) },  pr = (w[v][u], w[v][u+1]-w[v][u])
// grid (96 p, 32 chunks), block 256. No masks.
// ---------------------------------------------------------------------------
__global__ __launch_bounds__(256) void k_bp2d(const unsigned* __restrict__ derivp,
                                              unsigned* __restrict__ wq_dw) {
    __shared__ float sc[NANG], ss[NANG];
    __shared__ float buf[512];
    const int p   = blockIdx.x;
    const int tid = threadIdx.x;

    if (tid < NANG) {
        float s_, c_;
        sincosf((float)tid * (float)(3.14159265358979323846 / 96.0), &s_, &c_);
        sc[tid] = c_; ss[tid] = s_;
    }

    const int pixbase = blockIdx.y * 512;
    float acc[2], fx[2], fy[2];
    #pragma unroll
    for (int i = 0; i < 2; ++i) {
        const int pix = pixbase + i*256 + tid;
        fx[i] = (float)(pix & 127) - 63.5f;
        fy[i] = (float)(pix >> 7)  - 63.5f;
        acc[i] = 0.0f;
    }
    __syncthreads();   // trig ready

    const v4i rsrc = make_srsrc(derivp, NPROJ * SLICE * 4u);
    int soff = p * (SLICE * 4);                 // byte offset of angle row
    for (int a = 0; a < NANG; ++a, soff += DET * 4) {
        const float cb = sc[a], sb = ss[a];
        #pragma unroll
        for (int i = 0; i < 2; ++i) {
            const float pos = fmaf(cb, fx[i], fmaf(sb, fy[i], 95.5f));
            const int   i0  = (int)pos;            // pos in [5,186]
            const float f   = ffract(pos);
            const unsigned q = llvm_buf_load_x1(rsrc, i0 << 2, soff, 0);
            acc[i] = FDOT2(as_h2(q), as_h2(pack2(1.0f, f)), acc[i]);
        }
    }

    #pragma unroll
    for (int i = 0; i < 2; ++i) {
        const float w = 1000.0f * rsqrtf(1000000.0f + fx[i]*fx[i] + fy[i]*fy[i]);
        buf[i*256 + tid] = acc[i] * w;
    }
    __syncthreads();

    // epilogue: row-pair layout, 2 dword stores per pixel
    unsigned* sq = wq_dw + p * (NPIX * 2);
    #pragma unroll
    for (int i = 0; i < 2; ++i) {
        const int l   = i*256 + tid;
        const int pix = pixbase + l;
        const int u   = pix & 127;
        const int v   = pix >> 7;
        const float v0 = buf[l];
        const float v1 = (u < 127) ? buf[l + 1] : 0.0f;   // u=127 pair unused
        const unsigned pr = pack2(v0, v1 - v0);
        sq[(((v << 7) + u) << 1)] = pr;                          // lo slot of row v
        if (v >= 1) sq[((((v - 1) << 7) + u) << 1) + 1] = pr;    // hi slot of row v-1
    }
}

// ---------------------------------------------------------------------------
// K3: 3D cone-beam backprojection + PReLU — intra-block beta-split:
//   block = 256 thr = 2 groups x 128; group g handles betas [48g, 48g+48)
//   for the SAME voxel column (x = tid&127, y = blockIdx.x, z0..z0+7).
//   End: 4 KB LDS exchange sums the halves, PReLU, store.
// This gives z=8/thread setup amortization (r1's proven -27% VALU) while
// keeping grid (128,16) = 2048 blocks = 32 waves/CU (r0's proven latency
// regime; r1's 16 waves/CU collapsed VALUBusy to 50%).
// Row-pair loads (no quad select chain) + SRSRC buffer gathers: 32-bit
// voffset = (ivA<<10)+ub in one v_lshl_add; beta slice advance is scalar
// soffset (+131072/beta).
// pu in [11,116], pv in [19,108] -> no masks.
// ---------------------------------------------------------------------------
__global__ __launch_bounds__(256) void k_bp3d_s(const unsigned* __restrict__ wp_raw,
                                                const float* __restrict__ prelu,
                                                float* __restrict__ out) {
    __shared__ float sc[NPROJ], ss[NPROJ];
    __shared__ float xch[2][4][128];      // [group][j][x] — conflict-free
    const int tid = threadIdx.x;
    const int x   = tid & 127;
    const int g   = tid >> 7;             // beta-half (wave-uniform)
    const int y   = blockIdx.x;
    const int z0  = blockIdx.y << 3;      // 8 z per thread

    if (tid < NPROJ) {
        float s_, c_;
        sincosf((float)tid * (float)(2.0 * 3.14159265358979323846 / 96.0), &s_, &c_);
        sc[tid] = c_; ss[tid] = s_;
    }

    const float fx  = (float)x - 63.5f;
    const float fy  = (float)y - 63.5f;
    const float zlo = (float)z0 - 63.5f;

    float acc[8];
    #pragma unroll
    for (int j = 0; j < 8; ++j) acc[j] = 0.0f;

    __syncthreads();   // trig ready

    const v4i rsrc = make_srsrc(wp_raw, NPROJ * NPIX * 8u);
    int soff = g * (48 * NPIX * 8);       // byte offset of beta slice
    const int btrig0 = g * 48;
    for (int b = 0; b < 48; ++b, soff += NPIX * 8) {
        const float cb    = sc[btrig0 + b], sb = ss[btrig0 + b];
        const float t     = fmaf(fx, cb,  fy * sb);
        const float sdist = fmaf(fy, cb, -fx * sb);
        const float invr  = frcp(500.0f + t);
        const float pu    = fmaf(KPROJ * sdist, invr, 63.5f);
        const int   iu0   = (int)pu;             // pu in [11, 116]
        const float fu    = ffract(pu);
        float w2 = 1000.0f * invr; w2 *= w2;
        const float Kz    = KPROJ * invr;
        const h2    wuw   = as_h2(pack2(w2, fu * w2));   // diff-pair weights
        const int   ub    = iu0 << 3;            // byte offset of column

        #pragma unroll
        for (int pr2 = 0; pr2 < 4; ++pr2) {      // z-pairs (0,1)..(6,7)
            const float pvA = fmaf(Kz, zlo + (float)(2*pr2), 63.5f);
            const float pvB = pvA + Kz;
            const int   ivA = (int)pvA;          // pv in [19, 108]
            const int   ivB = (int)pvB;          // ivA or ivA+1
            const float fvA = ffract(pvA);
            const float fvB = ffract(pvB);
            const u32x2 qA  = llvm_buf_load_x2(rsrc, (ivA << 10) + ub, soff, 0);
            const u32x2 qB  = llvm_buf_load_x2(rsrc, (ivB << 10) + ub, soff, 0);
            const float tA  = FDOT2(as_h2(qA.x), wuw, 0.0f);
            const float bA  = FDOT2(as_h2(qA.y), wuw, 0.0f);
            acc[2*pr2]     += fmaf(fvA, bA - tA, tA);
            const float tB  = FDOT2(as_h2(qB.x), wuw, 0.0f);
            const float bB  = FDOT2(as_h2(qB.y), wuw, 0.0f);
            acc[2*pr2 + 1] += fmaf(fvB, bB - tB, tB);
        }
    }

    // publish the 4 accs the OTHER group will store
    #pragma unroll
    for (int j = 0; j < 4; ++j) xch[g][j][x] = acc[4*(1 - g) + j];
    __syncthreads();

    const float a = prelu[0];
    #pragma unroll
    for (int j = 0; j < 4; ++j) {
        const int   jz = 4*g + j;
        const float v  = acc[jz] + xch[1 - g][j][x];
        out[((z0 + jz) << 14) + (y << 7) + x] = (v >= 0.0f) ? v : a * v;
    }
}

// ---------------------------------------------------------------------------
extern "C" void kernel_launch(void* const* d_in, const int* in_sizes, int n_in,
                              void* d_out, int out_size, void* d_ws, size_t ws_size,
                              hipStream_t stream) {
    const float* sino  = (const float*)d_in[0];   // (1,1,96,96,192)
    const float* wgt   = (const float*)d_in[1];   // (1,96,96,192)
    const float* prelu = (const float*)d_in[2];   // (1,)
    float* out = (float*)d_out;                   // 128^3 floats

    unsigned* wq_dw  = (unsigned*)d_ws;                        // 12.58 MB row-pairs
    unsigned* derivp = wq_dw + (size_t)NPROJ * NPIX * 2;       // 7.08 MB pairs

    k_deriv <<<dim3(NPROJ * NANG), dim3(192), 0, stream>>>(sino, wgt, derivp);
    k_bp2d  <<<dim3(NPROJ, 32),    dim3(256), 0, stream>>>(derivp, wq_dw);
    k_bp3d_s<<<dim3(128, 16),      dim3(256), 0, stream>>>(wq_dw, prelu, out);
}

// Round 4
// 196.770 us; speedup vs baseline: 1.0466x; 1.0466x over previous
//
#include <hip/hip_runtime.h>
#include <hip/hip_fp16.h>
#include <math.h>

#define NPROJ 96
#define NANG  96
#define DET   192
#define NPIX  16384            // 128*128
#define SLICE (NANG*DET)       // 18432

// DSD/DU = DSD/DV = 1000/3.5
#define KPROJ 285.7142857142857f

__device__ __forceinline__ float frcp(float x) { return __builtin_amdgcn_rcpf(x); }

__device__ __forceinline__ float ffract(float x) {
#if __has_builtin(__builtin_amdgcn_fractf)
    return __builtin_amdgcn_fractf(x);
#else
    return x - floorf(x);
#endif
}

typedef __fp16 h2 __attribute__((ext_vector_type(2)));

__device__ __forceinline__ unsigned pack2(float a, float b) {
    h2 p = __builtin_amdgcn_cvt_pkrtz(a, b);
    return __builtin_bit_cast(unsigned, p);
}
__device__ __forceinline__ h2 as_h2(unsigned u) { return __builtin_bit_cast(h2, u); }

#if __has_builtin(__builtin_amdgcn_fdot2)
#define FDOT2(a, b, c) __builtin_amdgcn_fdot2((a), (b), (c), false)
#else
__device__ __forceinline__ float FDOT2(h2 a, h2 b, float c) {
    return c + (float)a[0] * (float)b[0] + (float)a[1] * (float)b[1];
}
#endif

// ---------------------------------------------------------------------------
// K1: deriv = grad_lastdim(sino * weight) -> DIFFERENCE pairs:
// derivp[row][d] = half2(g[d], g[d+1]-g[d])  =>  lerp weight is (1, f).
// ---------------------------------------------------------------------------
__global__ __launch_bounds__(192) void k_deriv(const float* __restrict__ sino,
                                               const float* __restrict__ wgt,
                                               unsigned* __restrict__ derivp) {
    __shared__ float row[DET];
    const int r = blockIdx.x;          // p*96 + a
    const int d = threadIdx.x;         // 0..191
    const int base = r * DET + d;
    row[d] = sino[base] * wgt[base];
    __syncthreads();
    auto grad = [&](int i) -> float {
        i = (i > DET-1) ? DET-1 : i;
        if (i == 0)       return row[1] - row[0];
        if (i == DET-1)   return row[DET-1] - row[DET-2];
        return 0.5f * (row[i+1] - row[i-1]);
    };
    const float g0 = grad(d), g1 = grad(d+1);
    derivp[base] = pack2(g0, g1 - g0);
}

// ---------------------------------------------------------------------------
// K2: 2D backprojection + cosine weighting — r2 version verbatim (plain
// pointer gathers; SRSRC bought nothing measurable here).
// Main loop: 2 px/thread at STRIDE 256, diff-pair weights (1, f), 1 dword
// gather per px-angle.
// Epilogue: every-v ROW-PAIR layout (uint2 per (v,u)):
//   wp[p][v][u] = { pr(v,u), pr(v+1,u) },  pr = (w[v][u], w[v][u+1]-w[v][u])
// grid (96 p, 32 chunks), block 256. No masks.
// ---------------------------------------------------------------------------
__global__ __launch_bounds__(256) void k_bp2d(const unsigned* __restrict__ derivp,
                                              unsigned* __restrict__ wq_dw) {
    __shared__ float sc[NANG], ss[NANG];
    __shared__ float buf[512];
    const int p   = blockIdx.x;
    const int tid = threadIdx.x;

    if (tid < NANG) {
        float s_, c_;
        sincosf((float)tid * (float)(3.14159265358979323846 / 96.0), &s_, &c_);
        sc[tid] = c_; ss[tid] = s_;
    }

    const int pixbase = blockIdx.y * 512;
    float acc[2], fx[2], fy[2];
    #pragma unroll
    for (int i = 0; i < 2; ++i) {
        const int pix = pixbase + i*256 + tid;
        fx[i] = (float)(pix & 127) - 63.5f;
        fy[i] = (float)(pix >> 7)  - 63.5f;
        acc[i] = 0.0f;
    }
    __syncthreads();   // trig ready

    const unsigned* rowp = derivp + p * SLICE;   // advances by DET per angle
    for (int a = 0; a < NANG; ++a, rowp += DET) {
        const float cb = sc[a], sb = ss[a];
        #pragma unroll
        for (int i = 0; i < 2; ++i) {
            const float pos = fmaf(cb, fx[i], fmaf(sb, fy[i], 95.5f));
            const int   i0  = (int)pos;            // pos > 0 always
            const float f   = ffract(pos);
            acc[i] = FDOT2(as_h2(rowp[i0]), as_h2(pack2(1.0f, f)), acc[i]);
        }
    }

    #pragma unroll
    for (int i = 0; i < 2; ++i) {
        const float w = 1000.0f * rsqrtf(1000000.0f + fx[i]*fx[i] + fy[i]*fy[i]);
        buf[i*256 + tid] = acc[i] * w;
    }
    __syncthreads();

    // epilogue: row-pair layout, 2 dword stores per pixel
    unsigned* sq = wq_dw + p * (NPIX * 2);
    #pragma unroll
    for (int i = 0; i < 2; ++i) {
        const int l   = i*256 + tid;
        const int pix = pixbase + l;
        const int u   = pix & 127;
        const int v   = pix >> 7;
        const float v0 = buf[l];
        const float v1 = (u < 127) ? buf[l + 1] : 0.0f;   // u=127 pair unused
        const unsigned pr = pack2(v0, v1 - v0);
        sq[(((v << 7) + u) << 1)] = pr;                          // lo slot of row v
        if (v >= 1) sq[((((v - 1) << 7) + u) << 1) + 1] = pr;    // hi slot of row v-1
    }
}

// ---------------------------------------------------------------------------
// K3: 3D cone-beam backprojection + PReLU — beta-split z8, PLAIN loads.
// r3 post-mortem: SRSRC soffset = f(tid>>7) is wave-uniform but not provably
// so -> compiler waterfall-looped every gather (+26% busy). Reverted to the
// r1 inner loop (measured 60.9 us busy, plain 64-bit-addressed global
// loads) inside the r3 split harness (proven 32 waves/CU + correct LDS
// combine):
//   block = 256 thr = 2 groups x 128; group g does betas [48g,48g+48) for
//   the same column (x = tid&127, y = blockIdx.x, z0..z0+7); 4 KB LDS
//   exchange sums halves, PReLU, store. grid (128,16) = 2048 blocks.
// Group offset absorbed into the per-thread base pointer ONCE, outside the
// beta loop. pu in [11,116], pv in [19,108] -> no masks.
// ---------------------------------------------------------------------------
__global__ __launch_bounds__(256) void k_bp3d_s2(const uint2* __restrict__ wp,
                                                 const float* __restrict__ prelu,
                                                 float* __restrict__ out) {
    __shared__ float sc[NPROJ], ss[NPROJ];
    __shared__ float xch[2][4][128];      // [group][j][x] — conflict-free
    const int tid = threadIdx.x;
    const int x   = tid & 127;
    const int g   = tid >> 7;             // beta-half (wave-uniform)
    const int y   = blockIdx.x;
    const int z0  = blockIdx.y << 3;      // 8 z per thread

    if (tid < NPROJ) {
        float s_, c_;
        sincosf((float)tid * (float)(2.0 * 3.14159265358979323846 / 96.0), &s_, &c_);
        sc[tid] = c_; ss[tid] = s_;
    }

    const float fx  = (float)x - 63.5f;
    const float fy  = (float)y - 63.5f;
    float za[4];
    #pragma unroll
    for (int j = 0; j < 4; ++j) za[j] = (float)z0 - 63.5f + (float)(2*j);

    float acc[8];
    #pragma unroll
    for (int j = 0; j < 8; ++j) acc[j] = 0.0f;

    __syncthreads();   // trig ready

    // per-thread slice base: group offset folded in once
    const char* bbc = (const char*)wp + (size_t)g * (48u * NPIX * sizeof(uint2));
    const int btrig0 = g * 48;
    for (int b = 0; b < 48; ++b, bbc += (size_t)NPIX * sizeof(uint2)) {
        const float cb    = sc[btrig0 + b], sb = ss[btrig0 + b];
        const float t     = fmaf(fx, cb,  fy * sb);
        const float sdist = fmaf(fy, cb, -fx * sb);
        const float invr  = frcp(500.0f + t);
        const float pu    = fmaf(KPROJ * sdist, invr, 63.5f);
        const int   iu0   = (int)pu;             // pu in [11, 116]
        const float fu    = ffract(pu);
        float w2 = 1000.0f * invr; w2 *= w2;
        const float Kz    = KPROJ * invr;
        const h2    wuw   = as_h2(pack2(w2, fu * w2));   // diff-pair weights
        const unsigned ub = ((unsigned)iu0) << 3;        // byte offset of column

        #pragma unroll
        for (int pr2 = 0; pr2 < 4; ++pr2) {      // z-pairs (0,1)..(6,7)
            const float pvA = fmaf(Kz, za[pr2], 63.5f);
            const float pvB = pvA + Kz;
            const int   ivA = (int)pvA;          // pv in [19, 108]
            const int   ivB = (int)pvB;          // ivA or ivA+1
            const float fvA = ffract(pvA);
            const float fvB = ffract(pvB);
            const uint2 qA  = *(const uint2*)(bbc + ((((unsigned)ivA) << 10) + ub));
            const uint2 qB  = *(const uint2*)(bbc + ((((unsigned)ivB) << 10) + ub));
            const float tA  = FDOT2(as_h2(qA.x), wuw, 0.0f);
            const float bA  = FDOT2(as_h2(qA.y), wuw, 0.0f);
            acc[2*pr2]     += fmaf(fvA, bA - tA, tA);
            const float tB  = FDOT2(as_h2(qB.x), wuw, 0.0f);
            const float bB  = FDOT2(as_h2(qB.y), wuw, 0.0f);
            acc[2*pr2 + 1] += fmaf(fvB, bB - tB, tB);
        }
    }

    // publish the 4 accs the OTHER group will store
    #pragma unroll
    for (int j = 0; j < 4; ++j) xch[g][j][x] = acc[4*(1 - g) + j];
    __syncthreads();

    const float a = prelu[0];
    #pragma unroll
    for (int j = 0; j < 4; ++j) {
        const int   jz = 4*g + j;
        const float v  = acc[jz] + xch[1 - g][j][x];
        out[((z0 + jz) << 14) + (y << 7) + x] = (v >= 0.0f) ? v : a * v;
    }
}

// ---------------------------------------------------------------------------
extern "C" void kernel_launch(void* const* d_in, const int* in_sizes, int n_in,
                              void* d_out, int out_size, void* d_ws, size_t ws_size,
                              hipStream_t stream) {
    const float* sino  = (const float*)d_in[0];   // (1,1,96,96,192)
    const float* wgt   = (const float*)d_in[1];   // (1,96,96,192)
    const float* prelu = (const float*)d_in[2];   // (1,)
    float* out = (float*)d_out;                   // 128^3 floats

    unsigned* wq_dw  = (unsigned*)d_ws;                        // 12.58 MB row-pairs
    unsigned* derivp = wq_dw + (size_t)NPROJ * NPIX * 2;       // 7.08 MB pairs

    k_deriv  <<<dim3(NPROJ * NANG), dim3(192), 0, stream>>>(sino, wgt, derivp);
    k_bp2d   <<<dim3(NPROJ, 32),    dim3(256), 0, stream>>>(derivp, wq_dw);
    k_bp3d_s2<<<dim3(128, 16),      dim3(256), 0, stream>>>((const uint2*)wq_dw, prelu, out);
}

// Round 5
// 184.883 us; speedup vs baseline: 1.1139x; 1.0643x over previous
//
#include <hip/hip_runtime.h>
#include <hip/hip_fp16.h>
#include <math.h>

#define NPROJ 96
#define NANG  96
#define DET   192
#define NPIX  16384            // 128*128
#define SLICE (NANG*DET)       // 18432

// DSD/DU = DSD/DV = 1000/3.5
#define KPROJ 285.7142857142857f

__device__ __forceinline__ float frcp(float x) { return __builtin_amdgcn_rcpf(x); }

__device__ __forceinline__ float ffract(float x) {
#if __has_builtin(__builtin_amdgcn_fractf)
    return __builtin_amdgcn_fractf(x);
#else
    return x - floorf(x);
#endif
}

typedef __fp16 h2 __attribute__((ext_vector_type(2)));

__device__ __forceinline__ unsigned pack2(float a, float b) {
    h2 p = __builtin_amdgcn_cvt_pkrtz(a, b);
    return __builtin_bit_cast(unsigned, p);
}
__device__ __forceinline__ h2 as_h2(unsigned u) { return __builtin_bit_cast(h2, u); }

#if __has_builtin(__builtin_amdgcn_fdot2)
#define FDOT2(a, b, c) __builtin_amdgcn_fdot2((a), (b), (c), false)
#else
__device__ __forceinline__ float FDOT2(h2 a, h2 b, float c) {
    return c + (float)a[0] * (float)b[0] + (float)a[1] * (float)b[1];
}
#endif

// ---------------------------------------------------------------------------
// K1: deriv = grad_lastdim(sino * weight) -> DIFFERENCE pairs:
// derivp[row][d] = half2(g[d], g[d+1]-g[d])  =>  lerp weight is (1, f).
// ---------------------------------------------------------------------------
__global__ __launch_bounds__(192) void k_deriv(const float* __restrict__ sino,
                                               const float* __restrict__ wgt,
                                               unsigned* __restrict__ derivp) {
    __shared__ float row[DET];
    const int r = blockIdx.x;          // p*96 + a
    const int d = threadIdx.x;         // 0..191
    const int base = r * DET + d;
    row[d] = sino[base] * wgt[base];
    __syncthreads();
    auto grad = [&](int i) -> float {
        i = (i > DET-1) ? DET-1 : i;
        if (i == 0)       return row[1] - row[0];
        if (i == DET-1)   return row[DET-1] - row[DET-2];
        return 0.5f * (row[i+1] - row[i-1]);
    };
    const float g0 = grad(d), g1 = grad(d+1);
    derivp[base] = pack2(g0, g1 - g0);
}

// ---------------------------------------------------------------------------
// K2: 2D backprojection + cosine weighting — r0 winner verbatim:
// 2 px/thread at STRIDE 256. Diff-pair weights (1, f). 1 dword gather/px-angle.
// Epilogue writes every-v QUAD layout in DIFFERENCE form:
//   wq[p][v][u] = uint4 of dpr(v..v+3,u), dpr = (w[v][u], w[v][u+1]-w[v][u]).
// grid (96 p, 32 chunks), block 256. No masks.
// ---------------------------------------------------------------------------
__global__ __launch_bounds__(256) void k_bp2d(const unsigned* __restrict__ derivp,
                                              unsigned* __restrict__ wq_dw) {
    __shared__ float sc[NANG], ss[NANG];
    __shared__ float buf[512];
    const int p   = blockIdx.x;
    const int tid = threadIdx.x;

    if (tid < NANG) {
        float s_, c_;
        sincosf((float)tid * (float)(3.14159265358979323846 / 96.0), &s_, &c_);
        sc[tid] = c_; ss[tid] = s_;
    }

    const int pixbase = blockIdx.y * 512;
    float acc[2], fx[2], fy[2];
    #pragma unroll
    for (int i = 0; i < 2; ++i) {
        const int pix = pixbase + i*256 + tid;
        fx[i] = (float)(pix & 127) - 63.5f;
        fy[i] = (float)(pix >> 7)  - 63.5f;
        acc[i] = 0.0f;
    }
    __syncthreads();   // trig ready

    const unsigned* rowp = derivp + p * SLICE;   // advances by DET per angle
    for (int a = 0; a < NANG; ++a, rowp += DET) {
        const float cb = sc[a], sb = ss[a];
        #pragma unroll
        for (int i = 0; i < 2; ++i) {
            const float pos = fmaf(cb, fx[i], fmaf(sb, fy[i], 95.5f));
            const int   i0  = (int)pos;            // pos > 0 always
            const float f   = ffract(pos);
            acc[i] = FDOT2(as_h2(rowp[i0]), as_h2(pack2(1.0f, f)), acc[i]);
        }
    }

    #pragma unroll
    for (int i = 0; i < 2; ++i) {
        const float w = 1000.0f * rsqrtf(1000000.0f + fx[i]*fx[i] + fy[i]*fy[i]);
        buf[i*256 + tid] = acc[i] * w;
    }
    __syncthreads();

    // epilogue: difference-pair of row v lands in slot k of quad v-k, k=0..3
    unsigned* sq = wq_dw + p * (NPIX * 4);
    #pragma unroll
    for (int i = 0; i < 2; ++i) {
        const int l   = i*256 + tid;
        const int pix = pixbase + l;
        const int u   = pix & 127;
        const int v   = pix >> 7;
        const float v0 = buf[l];
        const float v1 = (u < 127) ? buf[l + 1] : 0.0f;   // u=127 pair unused
        const unsigned pr = pack2(v0, v1 - v0);
        #pragma unroll
        for (int k = 0; k < 4; ++k) {
            const int vb = v - k;
            if (vb >= 0) sq[(((vb << 7) + u) << 2) + k] = pr;
        }
    }
}

// ---------------------------------------------------------------------------
// K3: 3D cone-beam backprojection + PReLU — r0 quad-z4 (proven 97.7 us,
// 85% VALUBusy) + explicit 2-deep ping-pong beta pipeline.
// r0's residual 15% idle = exposed L2 latency: at VGPR_Count=20 the
// allocator left no room to hoist loads, so each beta's 2 quad gathers were
// issued-then-waited. Fix: STAGE(b+1) (per-beta scalars + issue both quad
// loads) BEFORE MATH(b); ping-pong named structs (static indexing, rule
// #20); __launch_bounds__(256,8) gives the allocator 64 VGPR — free, since
// grid (64,32) = 2048 blocks = exactly 8 blocks/CU = 32 waves/CU cap.
// pu in [11,116], pv in [19,108] -> no masks.
// ---------------------------------------------------------------------------
struct BStage {
    uint4 q0, q1;            // quad rows ivA..ivA+3 for z-pairs 0,1
    h2    wuw;               // (w2, fu*w2) diff-pair u-weights
    float fvA0, fvB0, fvA1, fvB1;
    int   d0, d1;            // ivB - ivA per z-pair (0 or 1)
};

__global__ __launch_bounds__(256, 8) void k_bp3d_q2(const uint4* __restrict__ wq,
                                                    const float* __restrict__ prelu,
                                                    float* __restrict__ out) {
    __shared__ float sc[NPROJ], ss[NPROJ];
    const int tid = threadIdx.x;
    const int x   = tid & 127;
    const int y   = (blockIdx.x << 1) | (tid >> 7);
    const int z0  = blockIdx.y << 2;

    if (tid < NPROJ) {
        float s_, c_;
        sincosf((float)tid * (float)(2.0 * 3.14159265358979323846 / 96.0), &s_, &c_);
        sc[tid] = c_; ss[tid] = s_;
    }

    const float fx  = (float)x - 63.5f;
    const float fy  = (float)y - 63.5f;
    const float zlo = (float)z0 - 63.5f;

    float acc[4];
    #pragma unroll
    for (int j = 0; j < 4; ++j) acc[j] = 0.0f;

    __syncthreads();   // trig ready — the only barrier

    const char* basep = (const char*)wq;

    auto STAGE = [&](int b, BStage& S) {
        const float cb    = sc[b], sb = ss[b];
        const float t     = fmaf(fx, cb,  fy * sb);
        const float sdist = fmaf(fy, cb, -fx * sb);
        const float invr  = frcp(500.0f + t);
        const float pu    = fmaf(KPROJ * sdist, invr, 63.5f);
        const int   iu0   = (int)pu;             // pu in [11, 116]
        const float fu    = ffract(pu);
        float w2 = 1000.0f * invr; w2 *= w2;
        const float Kz    = KPROJ * invr;
        S.wuw = as_h2(pack2(w2, fu * w2));
        const unsigned ub = ((unsigned)iu0) << 4;              // 16B quad entries
        const char* sp    = basep + (size_t)(unsigned)b * (NPIX * sizeof(uint4));

        const float pvA0 = fmaf(Kz, zlo,        63.5f);
        const float pvB0 = pvA0 + Kz;
        const int   ivA0 = (int)pvA0;            // pv in [19, 108]
        S.d0    = (int)pvB0 - ivA0;
        S.fvA0  = ffract(pvA0);
        S.fvB0  = ffract(pvB0);
        S.q0    = *(const uint4*)(sp + ((((unsigned)ivA0) << 11) + ub));

        const float pvA1 = fmaf(Kz, zlo + 2.0f, 63.5f);
        const float pvB1 = pvA1 + Kz;
        const int   ivA1 = (int)pvA1;
        S.d1    = (int)pvB1 - ivA1;
        S.fvA1  = ffract(pvA1);
        S.fvB1  = ffract(pvB1);
        S.q1    = *(const uint4*)(sp + ((((unsigned)ivA1) << 11) + ub));
    };

    auto MATH = [&](const BStage& S) {
        // z-pair 0
        {
            const float tA = FDOT2(as_h2(S.q0.x), S.wuw, 0.0f);
            const float bA = FDOT2(as_h2(S.q0.y), S.wuw, 0.0f);
            acc[0] += fmaf(S.fvA0, bA - tA, tA);
            const unsigned tBv = S.d0 ? S.q0.y : S.q0.x;
            const unsigned bBv = S.d0 ? S.q0.z : S.q0.y;
            const float tB = FDOT2(as_h2(tBv), S.wuw, 0.0f);
            const float bB = FDOT2(as_h2(bBv), S.wuw, 0.0f);
            acc[1] += fmaf(S.fvB0, bB - tB, tB);
        }
        // z-pair 1
        {
            const float tA = FDOT2(as_h2(S.q1.x), S.wuw, 0.0f);
            const float bA = FDOT2(as_h2(S.q1.y), S.wuw, 0.0f);
            acc[2] += fmaf(S.fvA1, bA - tA, tA);
            const unsigned tBv = S.d1 ? S.q1.y : S.q1.x;
            const unsigned bBv = S.d1 ? S.q1.z : S.q1.y;
            const float tB = FDOT2(as_h2(tBv), S.wuw, 0.0f);
            const float bB = FDOT2(as_h2(bBv), S.wuw, 0.0f);
            acc[3] += fmaf(S.fvB1, bB - tB, tB);
        }
    };

    BStage sA, sB;
    STAGE(0, sA);
    for (int b = 0; b < 94; b += 2) {
        STAGE(b + 1, sB);  MATH(sA);     // sA's loads are one stage old
        STAGE(b + 2, sA);  MATH(sB);
    }
    STAGE(95, sB);  MATH(sA);  MATH(sB); // betas 94, 95

    const float a = prelu[0];
    #pragma unroll
    for (int j = 0; j < 4; ++j) {
        const float v = acc[j];
        out[((z0 + j) << 14) + (y << 7) + x] = (v >= 0.0f) ? v : a * v;
    }
}

// ---------------------------------------------------------------------------
extern "C" void kernel_launch(void* const* d_in, const int* in_sizes, int n_in,
                              void* d_out, int out_size, void* d_ws, size_t ws_size,
                              hipStream_t stream) {
    const float* sino  = (const float*)d_in[0];   // (1,1,96,96,192)
    const float* wgt   = (const float*)d_in[1];   // (1,96,96,192)
    const float* prelu = (const float*)d_in[2];   // (1,)
    float* out = (float*)d_out;                   // 128^3 floats

    unsigned* wq_dw  = (unsigned*)d_ws;                        // 25.17 MB quads
    unsigned* derivp = wq_dw + (size_t)NPROJ * NPIX * 4;       // 7.08 MB pairs

    k_deriv  <<<dim3(NPROJ * NANG), dim3(192), 0, stream>>>(sino, wgt, derivp);
    k_bp2d   <<<dim3(NPROJ, 32),    dim3(256), 0, stream>>>(derivp, wq_dw);
    k_bp3d_q2<<<dim3(64, 32),       dim3(256), 0, stream>>>((const uint4*)wq_dw, prelu, out);
}

// Round 6
// 184.182 us; speedup vs baseline: 1.1181x; 1.0038x over previous
//
#include <hip/hip_runtime.h>
#include <hip/hip_fp16.h>
#include <math.h>

#define NPROJ 96
#define NANG  96
#define DET   192
#define NPIX  16384            // 128*128
#define SLICE (NANG*DET)       // 18432

// wq stores quad rows [16,112) only (reads touch rows 19..111)
#define WQROW0   16
#define WQROWS   96
#define WQSLICEB (WQROWS*128*16)   // 196608 bytes per projection

// DSD/DU = DSD/DV = 1000/3.5
#define KPROJ 285.7142857142857f

__device__ __forceinline__ float frcp(float x) { return __builtin_amdgcn_rcpf(x); }

__device__ __forceinline__ float ffract(float x) {
#if __has_builtin(__builtin_amdgcn_fractf)
    return __builtin_amdgcn_fractf(x);
#else
    return x - floorf(x);
#endif
}

typedef __fp16 h2 __attribute__((ext_vector_type(2)));

__device__ __forceinline__ unsigned pack2(float a, float b) {
    h2 p = __builtin_amdgcn_cvt_pkrtz(a, b);
    return __builtin_bit_cast(unsigned, p);
}
__device__ __forceinline__ h2 as_h2(unsigned u) { return __builtin_bit_cast(h2, u); }

#if __has_builtin(__builtin_amdgcn_fdot2)
#define FDOT2(a, b, c) __builtin_amdgcn_fdot2((a), (b), (c), false)
#else
__device__ __forceinline__ float FDOT2(h2 a, h2 b, float c) {
    return c + (float)a[0] * (float)b[0] + (float)a[1] * (float)b[1];
}
#endif

// ---------------------------------------------------------------------------
// K1: deriv = grad_lastdim(sino * weight) -> DIFFERENCE pairs:
// derivp[row][d] = half2(g[d], g[d+1]-g[d])  =>  lerp weight is (1, f).
// ---------------------------------------------------------------------------
__global__ __launch_bounds__(192) void k_deriv(const float* __restrict__ sino,
                                               const float* __restrict__ wgt,
                                               unsigned* __restrict__ derivp) {
    __shared__ float row[DET];
    const int r = blockIdx.x;          // p*96 + a
    const int d = threadIdx.x;         // 0..191
    const int base = r * DET + d;
    row[d] = sino[base] * wgt[base];
    __syncthreads();
    auto grad = [&](int i) -> float {
        i = (i > DET-1) ? DET-1 : i;
        if (i == 0)       return row[1] - row[0];
        if (i == DET-1)   return row[DET-1] - row[DET-2];
        return 0.5f * (row[i+1] - row[i-1]);
    };
    const float g0 = grad(d), g1 = grad(d+1);
    derivp[base] = pack2(g0, g1 - g0);
}

// ---------------------------------------------------------------------------
// K2: 2D backprojection + cosine weighting — r0 winner main loop verbatim.
// Epilogue now ALSO emits the K3 per-(beta,pixel) prologue table:
//   tbl[p][pix] = { wuw = pack2(w2, fu*w2),  kzi = bits(Kz)&~127 | iu0 }
// (iu0 in Kz's low 7 mantissa bits: <=8e-6 rel perturbation of Kz, ~3e-4 px
// in pv — far below the fp16 quantization already in wq.)
// Quad layout trimmed to rows [16,112): wq[p][vb-16][u] quad of dpr rows
// vb..vb+3; reads touch ivA in [19,108] -> rows 19..111, all stored.
// grid (96 p, 32 chunks), block 256. No masks.
// ---------------------------------------------------------------------------
__global__ __launch_bounds__(256) void k_bp2d(const unsigned* __restrict__ derivp,
                                              unsigned* __restrict__ wq_dw,
                                              uint2* __restrict__ tbl) {
    __shared__ float sc[NANG], ss[NANG];
    __shared__ float buf[512];
    const int p   = blockIdx.x;
    const int tid = threadIdx.x;

    if (tid < NANG) {
        float s_, c_;
        sincosf((float)tid * (float)(3.14159265358979323846 / 96.0), &s_, &c_);
        sc[tid] = c_; ss[tid] = s_;
    }

    // K3 cone-beam geometry trig for this projection (uniform over block)
    float sb2, cb2;
    sincosf((float)p * (float)(2.0 * 3.14159265358979323846 / 96.0), &sb2, &cb2);

    const int pixbase = blockIdx.y * 512;
    float acc[2], fx[2], fy[2];
    #pragma unroll
    for (int i = 0; i < 2; ++i) {
        const int pix = pixbase + i*256 + tid;
        fx[i] = (float)(pix & 127) - 63.5f;
        fy[i] = (float)(pix >> 7)  - 63.5f;
        acc[i] = 0.0f;
    }
    __syncthreads();   // trig ready

    const unsigned* rowp = derivp + p * SLICE;   // advances by DET per angle
    for (int a = 0; a < NANG; ++a, rowp += DET) {
        const float cb = sc[a], sb = ss[a];
        #pragma unroll
        for (int i = 0; i < 2; ++i) {
            const float pos = fmaf(cb, fx[i], fmaf(sb, fy[i], 95.5f));
            const int   i0  = (int)pos;            // pos > 0 always
            const float f   = ffract(pos);
            acc[i] = FDOT2(as_h2(rowp[i0]), as_h2(pack2(1.0f, f)), acc[i]);
        }
    }

    #pragma unroll
    for (int i = 0; i < 2; ++i) {
        const float w = 1000.0f * rsqrtf(1000000.0f + fx[i]*fx[i] + fy[i]*fy[i]);
        buf[i*256 + tid] = acc[i] * w;
    }
    __syncthreads();

    unsigned* sq = wq_dw + p * (WQROWS * 128 * 4);
    uint2*    tp = tbl   + p * NPIX;
    #pragma unroll
    for (int i = 0; i < 2; ++i) {
        const int l   = i*256 + tid;
        const int pix = pixbase + l;
        const int u   = pix & 127;
        const int v   = pix >> 7;
        const float v0 = buf[l];
        const float v1 = (u < 127) ? buf[l + 1] : 0.0f;   // u=127 pair unused
        const unsigned pr = pack2(v0, v1 - v0);
        #pragma unroll
        for (int k = 0; k < 4; ++k) {
            const int vb = v - k;
            if (vb >= WQROW0 && vb < WQROW0 + WQROWS)
                sq[(((vb - WQROW0) << 7) + u) << 2 | k] = pr;
        }
        // K3 prologue table entry for (p, pix)
        const float t3   = fmaf(fx[i], cb2,  fy[i] * sb2);
        const float sd3  = fmaf(fy[i], cb2, -fx[i] * sb2);
        const float invr = frcp(500.0f + t3);
        const float pu   = fmaf(KPROJ * sd3, invr, 63.5f);
        const int   iu0  = (int)pu;              // [11,116]
        const float fu   = ffract(pu);
        float w2 = 1000.0f * invr; w2 *= w2;
        const float Kz   = KPROJ * invr;         // > 0
        const unsigned kzi = (__builtin_bit_cast(unsigned, Kz) & ~127u) | (unsigned)iu0;
        uint2 e; e.x = pack2(w2, fu * w2); e.y = kzi;
        tp[pix] = e;                             // coalesced dwordx2
    }
}

// ---------------------------------------------------------------------------
// K3: 3D cone-beam backprojection + PReLU — r0 quad-z4 MATH (proven best
// memory shape) with the per-beta scalar prologue REPLACED by a table load:
// per beta: 1 coalesced dwordx2 (prefetched one beta ahead) + 3 unpack ops
// instead of t/sdist/rcp/pu/fract/w2/pack (~18-20 slots, 32x redundant
// across z-chunks — now computed once, in K2). Per-beta VALU ~64 -> ~48.
// grid (64 y-pairs, 32 z-chunks) = 2048 blocks = 32 waves/CU. No LDS, no
// barriers, no trig. pu in [11,116], pv in [19,108] -> no masks.
// NOTE: the b=95 table prefetch reads one slice past tbl — lands in the
// derivp region of the same workspace allocation (valid memory, unused).
// ---------------------------------------------------------------------------
__global__ __launch_bounds__(256, 8) void k_bp3d_t(const unsigned char* __restrict__ wq,
                                                   const uint2* __restrict__ tbl,
                                                   const float* __restrict__ prelu,
                                                   float* __restrict__ out) {
    const int tid = threadIdx.x;
    const int x   = tid & 127;
    const int y   = (blockIdx.x << 1) | (tid >> 7);
    const int z0  = blockIdx.y << 2;
    const int pix = (y << 7) + x;

    const float zlo = (float)z0 - 63.5f;

    float acc[4];
    #pragma unroll
    for (int j = 0; j < 4; ++j) acc[j] = 0.0f;

    const uint2* tp = tbl + pix;
    const unsigned char* sp = wq;

    uint2 Tc = *tp; tp += NPIX;

    for (int b = 0; b < NPROJ; ++b, tp += NPIX, sp += WQSLICEB) {
        const uint2 Tn = *tp;                    // next-beta prefetch
        const h2    wuw = as_h2(Tc.x);
        const int   iu0 = (int)(Tc.y & 127u);
        const float Kz  = __builtin_bit_cast(float, Tc.y & ~127u);
        const int   ub2 = (iu0 << 4) - (WQROW0 << 11);   // fold row-trim offset

        // z-pair 0 (z0, z0+1)
        const float pvA0 = fmaf(Kz, zlo, 63.5f);
        const float pvB0 = pvA0 + Kz;
        const int   ivA0 = (int)pvA0;            // [19,108]
        const int   d0   = (int)pvB0 - ivA0;     // 0 or 1
        const float fvA0 = ffract(pvA0);
        const float fvB0 = ffract(pvB0);
        const uint4 q0   = *(const uint4*)(sp + ((ivA0 << 11) + ub2));

        // z-pair 1 (z0+2, z0+3)
        const float pvA1 = fmaf(Kz, zlo + 2.0f, 63.5f);
        const float pvB1 = pvA1 + Kz;
        const int   ivA1 = (int)pvA1;
        const int   d1   = (int)pvB1 - ivA1;
        const float fvA1 = ffract(pvA1);
        const float fvB1 = ffract(pvB1);
        const uint4 q1   = *(const uint4*)(sp + ((ivA1 << 11) + ub2));

        {
            const float tA = FDOT2(as_h2(q0.x), wuw, 0.0f);
            const float bA = FDOT2(as_h2(q0.y), wuw, 0.0f);
            acc[0] += fmaf(fvA0, bA - tA, tA);
            const unsigned tBv = d0 ? q0.y : q0.x;
            const unsigned bBv = d0 ? q0.z : q0.y;
            const float tB = FDOT2(as_h2(tBv), wuw, 0.0f);
            const float bB = FDOT2(as_h2(bBv), wuw, 0.0f);
            acc[1] += fmaf(fvB0, bB - tB, tB);
        }
        {
            const float tA = FDOT2(as_h2(q1.x), wuw, 0.0f);
            const float bA = FDOT2(as_h2(q1.y), wuw, 0.0f);
            acc[2] += fmaf(fvA1, bA - tA, tA);
            const unsigned tBv = d1 ? q1.y : q1.x;
            const unsigned bBv = d1 ? q1.z : q1.y;
            const float tB = FDOT2(as_h2(tBv), wuw, 0.0f);
            const float bB = FDOT2(as_h2(bBv), wuw, 0.0f);
            acc[3] += fmaf(fvB1, bB - tB, tB);
        }
        Tc = Tn;
    }

    const float a = prelu[0];
    #pragma unroll
    for (int j = 0; j < 4; ++j) {
        const float v = acc[j];
        out[((z0 + j) << 14) + (y << 7) + x] = (v >= 0.0f) ? v : a * v;
    }
}

// ---------------------------------------------------------------------------
extern "C" void kernel_launch(void* const* d_in, const int* in_sizes, int n_in,
                              void* d_out, int out_size, void* d_ws, size_t ws_size,
                              hipStream_t stream) {
    const float* sino  = (const float*)d_in[0];   // (1,1,96,96,192)
    const float* wgt   = (const float*)d_in[1];   // (1,96,96,192)
    const float* prelu = (const float*)d_in[2];   // (1,)
    float* out = (float*)d_out;                   // 128^3 floats

    unsigned char* wsb = (unsigned char*)d_ws;
    unsigned* wq_dw  = (unsigned*)wsb;                                   // 18.87 MB quads (rows 16..111)
    uint2*    tbl    = (uint2*)(wsb + (size_t)NPROJ * WQSLICEB);         // 12.58 MB table
    unsigned* derivp = (unsigned*)(wsb + (size_t)NPROJ * WQSLICEB
                                       + (size_t)NPROJ * NPIX * 8);      // 7.08 MB pairs

    k_deriv <<<dim3(NPROJ * NANG), dim3(192), 0, stream>>>(sino, wgt, derivp);
    k_bp2d  <<<dim3(NPROJ, 32),    dim3(256), 0, stream>>>(derivp, wq_dw, tbl);
    k_bp3d_t<<<dim3(64, 32),       dim3(256), 0, stream>>>((const unsigned char*)wq_dw, tbl, prelu, out);
}